// Round 14
// baseline (449.028 us; speedup 1.0000x reference)
//
#include <hip/hip_runtime.h>
#include <hip/hip_bf16.h>
#include <hip/hip_cooperative_groups.h>

namespace cg = cooperative_groups;

// Problem constants (B=1). All inputs/outputs are float32.
#define HH   96
#define WW   96
#define NPIX 9216          // 96*96
#define CH   128
#define NH   8
#define HD   16
#define KS   8

#define NPOS    120        // 8 window rows x 15 window cols per 16-px segment
#define KVPITCH 40         // attn LDS pitch in channels (80B/pos)
#define PMPITCH 392        // conv LDS tile pitch in channels

#define NBLK 1152

__device__ __forceinline__ unsigned short f2bf(float f) {
    __hip_bfloat16 b = __float2bfloat16(f);
    union { __hip_bfloat16 b; unsigned short u; } cv; cv.b = b; return cv.u;
}
// unpack uint4 = 8 bf16 -> 8 fp32
__device__ __forceinline__ void u4_to_f8(uint4 u, float* f) {
    f[0] = __uint_as_float(u.x << 16); f[1] = __uint_as_float(u.x & 0xffff0000u);
    f[2] = __uint_as_float(u.y << 16); f[3] = __uint_as_float(u.y & 0xffff0000u);
    f[4] = __uint_as_float(u.z << 16); f[5] = __uint_as_float(u.z & 0xffff0000u);
    f[6] = __uint_as_float(u.w << 16); f[7] = __uint_as_float(u.w & 0xffff0000u);
}

// ===========================================================================
// Shared device bodies (used by both the cooperative kernel and the
// standalone fallback kernels) — all R12-proven math.
// ===========================================================================

// depthwise 3x3 conv for a tile of `npx` pixels starting at (row, j0q);
// thread = (g = tid>>1, sh = tid&1 covering npx/2 px). Writes LDS tile then
// pixel-major global. npx must be even; LDS tile pitch PMPITCH.
template <int NPX>
__device__ __forceinline__ void conv_tile_body(
    const float* __restrict__ x, const float* __restrict__ w,
    const float* __restrict__ bias, unsigned short* __restrict__ qkv_pm,
    unsigned short* conv_tile, int row, int j0q, int tid)
{
    constexpr int HPX = NPX / 2;
    const int g  = tid >> 1;
    const int sh = tid & 1;
    const int j0 = j0q + sh * HPX;

    const float* xg = x + g * NPIX;

    float xr[3][HPX + 2];
    #pragma unroll
    for (int dr = 0; dr < 3; ++dr) {
        const int r = row + dr - 1;
        if (r >= 0 && r < HH) {
            #pragma unroll
            for (int m = 0; m < HPX + 2; ++m) {
                const int j = j0 + m - 1;
                xr[dr][m] = (j >= 0 && j < WW) ? xg[r * WW + j] : 0.f;
            }
        } else {
            #pragma unroll
            for (int m = 0; m < HPX + 2; ++m) xr[dr][m] = 0.f;
        }
    }

    #pragma unroll
    for (int dt = 0; dt < 3; ++dt) {
        const int o = 3 * g + dt;
        float w9[9];
        #pragma unroll
        for (int k = 0; k < 9; ++k) w9[k] = w[o * 9 + k];
        const float b = bias[o];

        #pragma unroll
        for (int px = 0; px < HPX; ++px) {
            float acc = b;
            #pragma unroll
            for (int kh = 0; kh < 3; ++kh)
                #pragma unroll
                for (int kw = 0; kw < 3; ++kw)
                    acc += xr[kh][px + kw] * w9[kh * 3 + kw];
            conv_tile[(sh * HPX + px) * PMPITCH + o] = f2bf(acc);
        }
    }

    __syncthreads();

    constexpr int NT = NPX * 48;
    #pragma unroll
    for (int it = 0; it < (NT + 255) / 256; ++it) {
        const int idx = it * 256 + tid;
        if (idx < NT) {
            const int px = idx / 48;
            const int c8 = idx - px * 48;
            const int o  = c8 * 8;
            const uint4 v = *(const uint4*)&conv_tile[px * PMPITCH + o];
            const int t = o >> 7, c = o & 127;
            *(uint4*)(qkv_pm + ((size_t)t * NPIX + row * WW + j0q + px) * CH + c) = v;
        }
    }
}

// attention body for one (seg, hp) vblock; kv = LDS [2][NPOS*KVPITCH].
__device__ __forceinline__ void attn_body(
    const unsigned short* __restrict__ qkv_pm, float* __restrict__ a_t,
    unsigned short (*kv)[NPOS * KVPITCH], int seg, int hp, int tid)
{
    const int i   = seg / 6;
    const int j0  = (seg - i * 6) * 16;
    const int rs     = 2 * min(max(i / 2 - 3, 0), 40);
    const int cs_min = 2 * min(max(j0 / 2 - 3, 0), 40);

    #pragma unroll
    for (int it = 0; it < 4; ++it) {
        const int idx = it * 256 + tid;
        if (idx < 960) {
            const int kvsel = idx / 480;
            const int rem   = idx - kvsel * 480;
            const int pos   = rem >> 2;
            const int sub   = rem & 3;
            const int p     = pos / 15;
            const int cc    = pos - p * 15;
            const int pixg  = (rs + 2 * p) * WW + cs_min + 2 * cc;  // < NPIX
            *(uint4*)&kv[kvsel][pos * KVPITCH + sub * 8] =
                *(const uint4*)(qkv_pm + ((size_t)(1 + kvsel) * NPIX + pixg) * CH
                                + hp * 32 + sub * 8);
        }
    }

    const int lane  = tid & 63;
    const int wave  = tid >> 6;
    const int r     = lane >> 3;
    const int hh    = (lane >> 2) & 1;
    const int px    = wave * 4 + (lane & 3);
    const int h     = hp * 2 + hh;
    const int pix   = seg * 16 + px;
    const int j     = j0 + px;
    const int ci0   = (2 * min(max(j / 2 - 3, 0), 40) - cs_min) >> 1;

    float qr[HD];
    {
        const unsigned short* qp = qkv_pm + (size_t)pix * CH + h * HD;
        u4_to_f8(*(const uint4*)qp, qr);
        u4_to_f8(*(const uint4*)(qp + 8), qr + 8);
        #pragma unroll
        for (int d = 0; d < HD; ++d) qr[d] *= 0.25f;   // HD^-0.5
    }

    __syncthreads();

    const int posr = r * 15 + ci0;
    float lg[KS];
    float m = -1e30f;
    #pragma unroll
    for (int q = 0; q < KS; ++q) {
        const unsigned short* kp = &kv[0][(posr + q) * KVPITCH + hh * HD];
        float kf[HD];
        u4_to_f8(*(const uint4*)kp, kf);
        u4_to_f8(*(const uint4*)(kp + 8), kf + 8);
        float acc = 0.f;
        #pragma unroll
        for (int d = 0; d < HD; ++d) acc += qr[d] * kf[d];
        lg[q] = acc;
        m = fmaxf(m, acc);
    }

    float s = 0.f;
    #pragma unroll
    for (int q = 0; q < KS; ++q) { lg[q] = __expf(lg[q] - m); s += lg[q]; }

    float o[HD];
    #pragma unroll
    for (int d = 0; d < HD; ++d) o[d] = 0.f;
    #pragma unroll
    for (int q = 0; q < KS; ++q) {
        const unsigned short* vp = &kv[1][(posr + q) * KVPITCH + hh * HD];
        float vf[HD];
        u4_to_f8(*(const uint4*)vp, vf);
        u4_to_f8(*(const uint4*)(vp + 8), vf + 8);
        const float wgt = lg[q];
        #pragma unroll
        for (int d = 0; d < HD; ++d) o[d] += wgt * vf[d];
    }

    #pragma unroll
    for (int mask = 8; mask <= 32; mask <<= 1) {
        const float m2 = __shfl_xor(m, mask);
        const float s2 = __shfl_xor(s, mask);
        const float mn = fmaxf(m, m2);
        const float ea = __expf(m - mn);
        const float eb = __expf(m2 - mn);
        s = s * ea + s2 * eb;
        #pragma unroll
        for (int d = 0; d < HD; ++d) {
            const float o2 = __shfl_xor(o[d], mask);
            o[d] = o[d] * ea + o2 * eb;
        }
        m = mn;
    }
    const float inv = 1.f / s;

    a_t[(size_t)(h * HD + 2 * r)     * NPIX + pix] = o[2 * r]     * inv;
    a_t[(size_t)(h * HD + 2 * r + 1) * NPIX + pix] = o[2 * r + 1] * inv;
}

// projection body for one 256-thread block index pblk in [0,576).
__device__ __forceinline__ void proj_body(
    const float* __restrict__ a_t, const float* __restrict__ pw,
    const float* __restrict__ pb, float* __restrict__ out, int pblk, int tid)
{
    const int idx = pblk * 256 + tid;
    const int op  = __builtin_amdgcn_readfirstlane(idx / 2304);
    const int pq  = idx - op * 2304;
    const int px0 = pq * 4;
    const int o0  = op * 2;

    float acc0[4], acc1[4];
    #pragma unroll
    for (int e = 0; e < 4; ++e) { acc0[e] = pb[o0]; acc1[e] = pb[o0 + 1]; }

    for (int c = 0; c < CH; ++c) {
        const float4 a  = *(const float4*)(a_t + (size_t)c * NPIX + px0);
        const float  w0 = pw[(o0)     * CH + c];
        const float  w1 = pw[(o0 + 1) * CH + c];
        acc0[0] += a.x * w0; acc0[1] += a.y * w0; acc0[2] += a.z * w0; acc0[3] += a.w * w0;
        acc1[0] += a.x * w1; acc1[1] += a.y * w1; acc1[2] += a.z * w1; acc1[3] += a.w * w1;
    }

    *(float4*)(out + (size_t)(o0)     * NPIX + px0) = make_float4(acc0[0], acc0[1], acc0[2], acc0[3]);
    *(float4*)(out + (size_t)(o0 + 1) * NPIX + px0) = make_float4(acc1[0], acc1[1], acc1[2], acc1[3]);
}

// ===========================================================================
// Path A: single cooperative kernel (conv -> sync -> attn -> sync -> proj)
// ===========================================================================
__global__ __launch_bounds__(256, 5) void fused_kernel(
    const float* __restrict__ x, const float* __restrict__ w,
    const float* __restrict__ bias, const float* __restrict__ pw,
    const float* __restrict__ pb, unsigned short* __restrict__ qkv_pm,
    float* __restrict__ a_t, float* __restrict__ out)
{
    __shared__ union SM {
        unsigned short conv_tile[8 * PMPITCH];      //  6,272 B
        unsigned short kv[2][NPOS * KVPITCH];       // 19,200 B
    } sm;

    cg::grid_group grid = cg::this_grid();
    const int tid = threadIdx.x;
    const int blk = blockIdx.x;

    {   // Phase 1: conv, 8-px tiles
        const int row = blk / 12;
        const int j0q = (blk - row * 12) * 8;
        conv_tile_body<8>(x, w, bias, qkv_pm, sm.conv_tile, row, j0q, tid);
    }

    grid.sync();

    #pragma unroll
    for (int k = 0; k < 2; ++k) {       // Phase 2: attention, 2 vblocks each
        __syncthreads();
        const int vb  = blk + k * NBLK;
        const int hp  = vb / 576;
        const int seg = vb - hp * 576;
        attn_body(qkv_pm, a_t, sm.kv, seg, hp, tid);
    }

    grid.sync();

    if (blk < 576)                       // Phase 3: projection
        proj_body(a_t, pw, pb, out, blk, tid);
}

// ===========================================================================
// Path B fallback: the R12-proven three kernels
// ===========================================================================
__global__ __launch_bounds__(256) void conv_pm_kernel(
    const float* __restrict__ x, const float* __restrict__ w,
    const float* __restrict__ bias, unsigned short* __restrict__ qkv_pm)
{
    __shared__ unsigned short ldst[24 * PMPITCH];   // 18,816 B
    const int row = blockIdx.x >> 2;
    const int q   = blockIdx.x & 3;
    conv_tile_body<24>(x, w, bias, qkv_pm, ldst, row, q * 24, threadIdx.x);
}

__global__ __launch_bounds__(256) void attn_kernel(
    const unsigned short* __restrict__ qkv_pm, float* __restrict__ a_t)
{
    __shared__ unsigned short kv[2][NPOS * KVPITCH];   // 19,200 B
    attn_body(qkv_pm, a_t, kv, blockIdx.x, blockIdx.y, threadIdx.x);
}

__global__ __launch_bounds__(256) void proj_kernel(
    const float* __restrict__ a_t, const float* __restrict__ pw,
    const float* __restrict__ pb, float* __restrict__ out)
{
    proj_body(a_t, pw, pb, out, blockIdx.x, threadIdx.x);
}

// ---------------------------------------------------------------------------
extern "C" void kernel_launch(void* const* d_in, const int* in_sizes, int n_in,
                              void* d_out, int out_size, void* d_ws, size_t ws_size,
                              hipStream_t stream)
{
    const float* x      = (const float*)d_in[0];
    const float* qkv_w  = (const float*)d_in[1];
    const float* qkv_b  = (const float*)d_in[2];
    const float* proj_w = (const float*)d_in[3];
    const float* proj_b = (const float*)d_in[4];
    float* out = (float*)d_out;

    unsigned short* qkv_pm = (unsigned short*)d_ws;            // [3][NPIX][CH] bf16
    float*          a_t    = (float*)(qkv_pm + 3 * NPIX * CH); // [CH][NPIX] fp32

    void* args[] = { (void*)&x, (void*)&qkv_w, (void*)&qkv_b, (void*)&proj_w,
                     (void*)&proj_b, (void*)&qkv_pm, (void*)&a_t, (void*)&out };
    hipError_t err = hipLaunchCooperativeKernel((const void*)fused_kernel,
                                                dim3(NBLK), dim3(256), args, 0, stream);
    if (err != hipSuccess) {
        // Fallback: proven R12 three-kernel pipeline (105.6 us).
        conv_pm_kernel<<<384, 256, 0, stream>>>(x, qkv_w, qkv_b, qkv_pm);
        attn_kernel   <<<dim3(576, 4), 256, 0, stream>>>(qkv_pm, a_t);
        proj_kernel   <<<576, 256, 0, stream>>>(a_t, proj_w, proj_b, out);
    }
}

// Round 15
// 412.948 us; speedup vs baseline: 1.0874x; 1.0874x over previous
//
#include <hip/hip_runtime.h>
#include <hip/hip_bf16.h>

// Problem constants (B=1). All inputs/outputs are float32.
#define HH   96
#define WW   96
#define NPIX 9216          // 96*96
#define CH   128
#define NH   8
#define HD   16
#define KS   8

#define NPOS    120        // 8 window rows x 15 window cols per 16-px segment
#define KVPITCH 40         // attn LDS pitch in channels (80B/pos)
#define PMPITCH 392        // conv LDS tile pitch in channels

#define NBLK 1152

__device__ __forceinline__ unsigned short f2bf(float f) {
    __hip_bfloat16 b = __float2bfloat16(f);
    union { __hip_bfloat16 b; unsigned short u; } cv; cv.b = b; return cv.u;
}
// unpack uint4 = 8 bf16 -> 8 fp32
__device__ __forceinline__ void u4_to_f8(uint4 u, float* f) {
    f[0] = __uint_as_float(u.x << 16); f[1] = __uint_as_float(u.x & 0xffff0000u);
    f[2] = __uint_as_float(u.y << 16); f[3] = __uint_as_float(u.y & 0xffff0000u);
    f[4] = __uint_as_float(u.z << 16); f[5] = __uint_as_float(u.z & 0xffff0000u);
    f[6] = __uint_as_float(u.w << 16); f[7] = __uint_as_float(u.w & 0xffff0000u);
}

// ===========================================================================
// R12-proven device bodies
// ===========================================================================

// depthwise 3x3 conv, 8-px tile at (row, j0q); thread = (g=tid>>1, sh=tid&1).
__device__ __forceinline__ void conv_tile8_body(
    const float* __restrict__ x, const float* __restrict__ w,
    const float* __restrict__ bias, unsigned short* __restrict__ qkv_pm,
    unsigned short* conv_tile, int row, int j0q, int tid)
{
    const int g  = tid >> 1;
    const int sh = tid & 1;
    const int j0 = j0q + sh * 4;

    const float* xg = x + g * NPIX;

    float xr[3][6];
    #pragma unroll
    for (int dr = 0; dr < 3; ++dr) {
        const int r = row + dr - 1;
        if (r >= 0 && r < HH) {
            #pragma unroll
            for (int m = 0; m < 6; ++m) {
                const int j = j0 + m - 1;
                xr[dr][m] = (j >= 0 && j < WW) ? xg[r * WW + j] : 0.f;
            }
        } else {
            #pragma unroll
            for (int m = 0; m < 6; ++m) xr[dr][m] = 0.f;
        }
    }

    #pragma unroll
    for (int dt = 0; dt < 3; ++dt) {
        const int o = 3 * g + dt;
        float w9[9];
        #pragma unroll
        for (int k = 0; k < 9; ++k) w9[k] = w[o * 9 + k];
        const float b = bias[o];

        #pragma unroll
        for (int px = 0; px < 4; ++px) {
            float acc = b;
            #pragma unroll
            for (int kh = 0; kh < 3; ++kh)
                #pragma unroll
                for (int kw = 0; kw < 3; ++kw)
                    acc += xr[kh][px + kw] * w9[kh * 3 + kw];
            conv_tile[(sh * 4 + px) * PMPITCH + o] = f2bf(acc);
        }
    }

    __syncthreads();

    // 8 px x 48 uint4 = 384 write tasks
    #pragma unroll
    for (int it = 0; it < 2; ++it) {
        const int idx = it * 256 + tid;
        if (idx < 384) {
            const int px = idx / 48;
            const int c8 = idx - px * 48;
            const int o  = c8 * 8;
            const uint4 v = *(const uint4*)&conv_tile[px * PMPITCH + o];
            const int t = o >> 7, c = o & 127;
            *(uint4*)(qkv_pm + ((size_t)t * NPIX + row * WW + j0q + px) * CH + c) = v;
        }
    }
}

// attention body for one (seg, hp) vblock; kv = LDS [2][NPOS*KVPITCH].
__device__ __forceinline__ void attn_body(
    const unsigned short* __restrict__ qkv_pm, float* __restrict__ a_t,
    unsigned short (*kv)[NPOS * KVPITCH], int seg, int hp, int tid)
{
    const int i   = seg / 6;
    const int j0  = (seg - i * 6) * 16;
    const int rs     = 2 * min(max(i / 2 - 3, 0), 40);
    const int cs_min = 2 * min(max(j0 / 2 - 3, 0), 40);

    #pragma unroll
    for (int it = 0; it < 4; ++it) {
        const int idx = it * 256 + tid;
        if (idx < 960) {
            const int kvsel = idx / 480;
            const int rem   = idx - kvsel * 480;
            const int pos   = rem >> 2;
            const int sub   = rem & 3;
            const int p     = pos / 15;
            const int cc    = pos - p * 15;
            const int pixg  = (rs + 2 * p) * WW + cs_min + 2 * cc;  // < NPIX
            *(uint4*)&kv[kvsel][pos * KVPITCH + sub * 8] =
                *(const uint4*)(qkv_pm + ((size_t)(1 + kvsel) * NPIX + pixg) * CH
                                + hp * 32 + sub * 8);
        }
    }

    const int lane  = tid & 63;
    const int wave  = tid >> 6;
    const int r     = lane >> 3;
    const int hh    = (lane >> 2) & 1;
    const int px    = wave * 4 + (lane & 3);
    const int h     = hp * 2 + hh;
    const int pix   = seg * 16 + px;
    const int j     = j0 + px;
    const int ci0   = (2 * min(max(j / 2 - 3, 0), 40) - cs_min) >> 1;

    float qr[HD];
    {
        const unsigned short* qp = qkv_pm + (size_t)pix * CH + h * HD;
        u4_to_f8(*(const uint4*)qp, qr);
        u4_to_f8(*(const uint4*)(qp + 8), qr + 8);
        #pragma unroll
        for (int d = 0; d < HD; ++d) qr[d] *= 0.25f;   // HD^-0.5
    }

    __syncthreads();

    const int posr = r * 15 + ci0;
    float lg[KS];
    float m = -1e30f;
    #pragma unroll
    for (int q = 0; q < KS; ++q) {
        const unsigned short* kp = &kv[0][(posr + q) * KVPITCH + hh * HD];
        float kf[HD];
        u4_to_f8(*(const uint4*)kp, kf);
        u4_to_f8(*(const uint4*)(kp + 8), kf + 8);
        float acc = 0.f;
        #pragma unroll
        for (int d = 0; d < HD; ++d) acc += qr[d] * kf[d];
        lg[q] = acc;
        m = fmaxf(m, acc);
    }

    float s = 0.f;
    #pragma unroll
    for (int q = 0; q < KS; ++q) { lg[q] = __expf(lg[q] - m); s += lg[q]; }

    float o[HD];
    #pragma unroll
    for (int d = 0; d < HD; ++d) o[d] = 0.f;
    #pragma unroll
    for (int q = 0; q < KS; ++q) {
        const unsigned short* vp = &kv[1][(posr + q) * KVPITCH + hh * HD];
        float vf[HD];
        u4_to_f8(*(const uint4*)vp, vf);
        u4_to_f8(*(const uint4*)(vp + 8), vf + 8);
        const float wgt = lg[q];
        #pragma unroll
        for (int d = 0; d < HD; ++d) o[d] += wgt * vf[d];
    }

    #pragma unroll
    for (int mask = 8; mask <= 32; mask <<= 1) {
        const float m2 = __shfl_xor(m, mask);
        const float s2 = __shfl_xor(s, mask);
        const float mn = fmaxf(m, m2);
        const float ea = __expf(m - mn);
        const float eb = __expf(m2 - mn);
        s = s * ea + s2 * eb;
        #pragma unroll
        for (int d = 0; d < HD; ++d) {
            const float o2 = __shfl_xor(o[d], mask);
            o[d] = o[d] * ea + o2 * eb;
        }
        m = mn;
    }
    const float inv = 1.f / s;

    a_t[(size_t)(h * HD + 2 * r)     * NPIX + pix] = o[2 * r]     * inv;
    a_t[(size_t)(h * HD + 2 * r + 1) * NPIX + pix] = o[2 * r + 1] * inv;
}

// projection body for one 256-thread block index pblk in [0,576).
__device__ __forceinline__ void proj_body(
    const float* __restrict__ a_t, const float* __restrict__ pw,
    const float* __restrict__ pb, float* __restrict__ out, int pblk, int tid)
{
    const int idx = pblk * 256 + tid;
    const int op  = __builtin_amdgcn_readfirstlane(idx / 2304);
    const int pq  = idx - op * 2304;
    const int px0 = pq * 4;
    const int o0  = op * 2;

    float acc0[4], acc1[4];
    #pragma unroll
    for (int e = 0; e < 4; ++e) { acc0[e] = pb[o0]; acc1[e] = pb[o0 + 1]; }

    for (int c = 0; c < CH; ++c) {
        const float4 a  = *(const float4*)(a_t + (size_t)c * NPIX + px0);
        const float  w0 = pw[(o0)     * CH + c];
        const float  w1 = pw[(o0 + 1) * CH + c];
        acc0[0] += a.x * w0; acc0[1] += a.y * w0; acc0[2] += a.z * w0; acc0[3] += a.w * w0;
        acc1[0] += a.x * w1; acc1[1] += a.y * w1; acc1[2] += a.z * w1; acc1[3] += a.w * w1;
    }

    *(float4*)(out + (size_t)(o0)     * NPIX + px0) = make_float4(acc0[0], acc0[1], acc0[2], acc0[3]);
    *(float4*)(out + (size_t)(o0 + 1) * NPIX + px0) = make_float4(acc1[0], acc1[1], acc1[2], acc1[3]);
}

// ===========================================================================
// Single kernel, producer-consumer flags (no grid.sync).
// Grid 1152 x 256, LDS 19.2 KB, __launch_bounds__(256,8) -> 8 blocks/CU
// capacity (2048 >= 1152 co-resident; r14 empirically confirmed).
// rowcnt[96]: conv row completion (target 12). segcnt[576]: attn seg
// completion (target 4). Release = __syncthreads (drains stores) + agent
// release fence + relaxed atomicAdd. Acquire = relaxed spin + agent acquire.
// ===========================================================================
__global__ __launch_bounds__(256, 8) void fused_flags_kernel(
    const float* __restrict__ x, const float* __restrict__ w,
    const float* __restrict__ bias, const float* __restrict__ pw,
    const float* __restrict__ pb, int* rowcnt, int* segcnt,
    unsigned short* __restrict__ qkv_pm, float* __restrict__ a_t,
    float* __restrict__ out)
{
    __shared__ union SM {
        unsigned short conv_tile[8 * PMPITCH];      //  6,272 B
        unsigned short kv[2][NPOS * KVPITCH];       // 19,200 B
    } sm;

    const int tid = threadIdx.x;
    const int blk = blockIdx.x;

    // ---- Phase 1: conv, 8-px tile ----
    const int crow = blk / 12;
    const int j0q  = (blk - crow * 12) * 8;
    conv_tile8_body(x, w, bias, qkv_pm, sm.conv_tile, crow, j0q, tid);

    __syncthreads();                    // all waves' global stores drained
    if (tid == 0) {
        __builtin_amdgcn_fence(__ATOMIC_RELEASE, "agent");
        __hip_atomic_fetch_add(&rowcnt[crow], 1, __ATOMIC_RELAXED,
                               __HIP_MEMORY_SCOPE_AGENT);
    }

    // ---- Phase 2: attention, 2 vblocks ----
    #pragma unroll
    for (int k = 0; k < 2; ++k) {
        const int vb  = blk + k * NBLK;         // 0..2303
        const int hp  = vb / 576;
        const int seg = vb - hp * 576;
        const int i   = seg / 6;
        const int rs  = 2 * min(max(i / 2 - 3, 0), 40);

        __syncthreads();                        // LDS reuse guard
        if (tid < 9) {                          // 8 window rows + own row i
            const int rr = (tid < 8) ? (rs + 2 * tid) : i;
            while (__hip_atomic_load(&rowcnt[rr], __ATOMIC_RELAXED,
                                     __HIP_MEMORY_SCOPE_AGENT) < 12)
                __builtin_amdgcn_s_sleep(2);
        }
        __syncthreads();
        __builtin_amdgcn_fence(__ATOMIC_ACQUIRE, "agent");

        attn_body(qkv_pm, a_t, sm.kv, seg, hp, tid);

        __syncthreads();                        // a_t stores drained
        if (tid == 0) {
            __builtin_amdgcn_fence(__ATOMIC_RELEASE, "agent");
            __hip_atomic_fetch_add(&segcnt[seg], 1, __ATOMIC_RELAXED,
                                   __HIP_MEMORY_SCOPE_AGENT);
        }
    }

    // ---- Phase 3: projection (blocks 0..575) ----
    if (blk < 576) {
        const int s0 = (blk % 9) * 64;          // 64-seg stripe
        if (tid < 64) {
            while (__hip_atomic_load(&segcnt[s0 + tid], __ATOMIC_RELAXED,
                                     __HIP_MEMORY_SCOPE_AGENT) < 4)
                __builtin_amdgcn_s_sleep(2);
        }
        __syncthreads();
        __builtin_amdgcn_fence(__ATOMIC_ACQUIRE, "agent");

        proj_body(a_t, pw, pb, out, blk, tid);
    }
}

// ---------------------------------------------------------------------------
extern "C" void kernel_launch(void* const* d_in, const int* in_sizes, int n_in,
                              void* d_out, int out_size, void* d_ws, size_t ws_size,
                              hipStream_t stream)
{
    const float* x      = (const float*)d_in[0];
    const float* qkv_w  = (const float*)d_in[1];
    const float* qkv_b  = (const float*)d_in[2];
    const float* proj_w = (const float*)d_in[3];
    const float* proj_b = (const float*)d_in[4];
    float* out = (float*)d_out;

    // ws layout: [flags 4096 B][qkv_pm bf16 7.08 MB][a_t fp32 4.72 MB]
    int*            rowcnt = (int*)d_ws;                       // [96]
    int*            segcnt = rowcnt + 96;                      // [576]
    unsigned short* qkv_pm = (unsigned short*)((char*)d_ws + 4096);
    float*          a_t    = (float*)(qkv_pm + 3 * NPIX * CH);

    hipMemsetAsync(d_ws, 0, 4096, stream);     // zero flags (graph-safe)

    fused_flags_kernel<<<NBLK, 256, 0, stream>>>(
        x, qkv_w, qkv_b, proj_w, proj_b, rowcnt, segcnt, qkv_pm, a_t, out);
}

// Round 16
// 105.885 us; speedup vs baseline: 4.2407x; 3.9000x over previous
//
#include <hip/hip_runtime.h>
#include <hip/hip_bf16.h>

// Problem constants (B=1). All inputs/outputs are float32.
#define HH   96
#define WW   96
#define NPIX 9216          // 96*96
#define CH   128
#define NH   8
#define HD   16
#define KS   8

#define NPOS    120        // 8 window rows x 15 window cols per 16-px segment
#define KVP32   36         // fp32 kv LDS pitch in dwords (144B/pos, 16B-aligned)
#define PMPITCH 392        // conv LDS tile pitch in channels

__device__ __forceinline__ unsigned short f2bf(float f) {
    __hip_bfloat16 b = __float2bfloat16(f);
    union { __hip_bfloat16 b; unsigned short u; } cv; cv.b = b; return cv.u;
}
// unpack uint4 = 8 bf16 -> 8 fp32
__device__ __forceinline__ void u4_to_f8(uint4 u, float* f) {
    f[0] = __uint_as_float(u.x << 16); f[1] = __uint_as_float(u.x & 0xffff0000u);
    f[2] = __uint_as_float(u.y << 16); f[3] = __uint_as_float(u.y & 0xffff0000u);
    f[4] = __uint_as_float(u.z << 16); f[5] = __uint_as_float(u.z & 0xffff0000u);
    f[6] = __uint_as_float(u.w << 16); f[7] = __uint_as_float(u.w & 0xffff0000u);
}

// ---------------------------------------------------------------------------
// K1: fused depthwise 3x3 conv + transpose -> pixel-major [3][NPIX][CH] bf16.
// (R12 proven, byte-identical) Quarter-row blocks: grid 384; block 256 thr.
// ---------------------------------------------------------------------------
__global__ __launch_bounds__(256) void conv_pm_kernel(
    const float* __restrict__ x,        // [128][96][96]
    const float* __restrict__ w,        // [384][1][3][3]
    const float* __restrict__ bias,     // [384]
    unsigned short* __restrict__ qkv_pm)// [3][NPIX][CH] bf16
{
    __shared__ unsigned short ldst[24 * PMPITCH];   // 18,816 B

    const int row = blockIdx.x >> 2;    // 0..95
    const int q   = blockIdx.x & 3;     // 0..3
    const int j0q = q * 24;
    const int tid = threadIdx.x;
    const int g   = tid >> 1;           // 0..127 input channel / group
    const int sh  = tid & 1;            // 0/1 -> 12 px each
    const int j0  = j0q + sh * 12;

    const float* xg = x + g * NPIX;

    float xr[3][14];
    #pragma unroll
    for (int dr = 0; dr < 3; ++dr) {
        const int r = row + dr - 1;
        if (r >= 0 && r < HH) {
            #pragma unroll
            for (int m = 0; m < 14; ++m) {
                const int j = j0 + m - 1;
                xr[dr][m] = (j >= 0 && j < WW) ? xg[r * WW + j] : 0.f;
            }
        } else {
            #pragma unroll
            for (int m = 0; m < 14; ++m) xr[dr][m] = 0.f;
        }
    }

    #pragma unroll
    for (int dt = 0; dt < 3; ++dt) {
        const int o = 3 * g + dt;       // conv out-channel (group g)
        float w9[9];
        #pragma unroll
        for (int k = 0; k < 9; ++k) w9[k] = w[o * 9 + k];
        const float b = bias[o];

        #pragma unroll
        for (int px = 0; px < 12; ++px) {
            float acc = b;
            #pragma unroll
            for (int kh = 0; kh < 3; ++kh)
                #pragma unroll
                for (int kw = 0; kw < 3; ++kw)
                    acc += xr[kh][px + kw] * w9[kh * 3 + kw];
            ldst[(sh * 12 + px) * PMPITCH + o] = f2bf(acc);
        }
    }

    __syncthreads();

    #pragma unroll
    for (int it = 0; it < 5; ++it) {
        const int idx = it * 256 + tid;
        if (idx < 1152) {
            const int px = idx / 48;
            const int c8 = idx - px * 48;
            const int o  = c8 * 8;
            const uint4 v = *(const uint4*)&ldst[px * PMPITCH + o];
            const int t = o >> 7, c = o & 127;
            *(uint4*)(qkv_pm + ((size_t)t * NPIX + row * WW + j0q + px) * CH + c) = v;
        }
    }
}

// ---------------------------------------------------------------------------
// K2: neighborhood attention, head-pair blocks, K/V staged as FP32 in LDS.
// Grid (576 segs, 4 head-pairs); block = 256 thr = 16 px x 2 heads x 8 r.
// Staging unpacks bf16->fp32 once (30 unpacks/thread) so the QK and PV hot
// loops are pure float4-LDS-read + fma (256 instrs vs 512 with inline
// unpack). LDS 2 x 120 x 36 dw = 34.6 KB -> 4 blocks/CU = 16 waves/CU.
// Read banks: addr = posr*36 + hh*16 dw; (28r + 16hh) mod 32 -> 2-way max.
// ---------------------------------------------------------------------------
__global__ __launch_bounds__(256) void attn_kernel(
    const unsigned short* __restrict__ qkv_pm,  // [3][NPIX][CH] bf16
    float* __restrict__ a_t)                    // [CH][NPIX] fp32
{
    __shared__ float kvK[NPOS * KVP32];         // 17,280 B
    __shared__ float kvV[NPOS * KVP32];         // 17,280 B

    const int tid = threadIdx.x;
    const int seg = blockIdx.x;                 // 0..575
    const int hp  = blockIdx.y;                 // head pair 0..3
    const int i   = seg / 6;                    // image row
    const int j0  = (seg - i * 6) * 16;
    const int rs     = 2 * min(max(i / 2 - 3, 0), 40);
    const int cs_min = 2 * min(max(j0 / 2 - 3, 0), 40);

    // ---- stage K,V (unpacked to fp32): 960 uint4 tasks ----
    #pragma unroll
    for (int it = 0; it < 4; ++it) {
        const int idx = it * 256 + tid;
        if (idx < 960) {
            const int kvsel = idx / 480;
            const int rem   = idx - kvsel * 480;
            const int pos   = rem >> 2;
            const int sub   = rem & 3;
            const int p     = pos / 15;
            const int cc    = pos - p * 15;
            const int pixg  = (rs + 2 * p) * WW + cs_min + 2 * cc;  // < NPIX
            const uint4 u = *(const uint4*)(qkv_pm
                + ((size_t)(1 + kvsel) * NPIX + pixg) * CH + hp * 32 + sub * 8);
            float f[8];
            u4_to_f8(u, f);
            float* dst = (kvsel ? kvV : kvK) + pos * KVP32 + sub * 8;
            *(float4*)(dst)     = make_float4(f[0], f[1], f[2], f[3]);
            *(float4*)(dst + 4) = make_float4(f[4], f[5], f[6], f[7]);
        }
    }

    // ---- per-thread coordinates: lane = r*8 + hh*4 + px_lo ----
    const int lane  = tid & 63;
    const int wave  = tid >> 6;                 // 0..3
    const int r     = lane >> 3;                // window-row split
    const int hh    = (lane >> 2) & 1;          // head within pair
    const int px    = wave * 4 + (lane & 3);    // 0..15
    const int h     = hp * 2 + hh;
    const int pix   = seg * 16 + px;
    const int j     = j0 + px;
    const int ci0   = (2 * min(max(j / 2 - 3, 0), 40) - cs_min) >> 1;  // 0..7

    float qr[HD];
    {
        const unsigned short* qp = qkv_pm + (size_t)pix * CH + h * HD;
        u4_to_f8(*(const uint4*)qp, qr);
        u4_to_f8(*(const uint4*)(qp + 8), qr + 8);
        #pragma unroll
        for (int d = 0; d < HD; ++d) qr[d] *= 0.25f;   // HD^-0.5
    }

    __syncthreads();

    // ---- QK^T for this thread's window row (pure fma) ----
    const int posr = r * 15 + ci0;
    float lg[KS];
    float m = -1e30f;
    #pragma unroll
    for (int q = 0; q < KS; ++q) {
        const float* kp = &kvK[(posr + q) * KVP32 + hh * HD];
        float acc = 0.f;
        #pragma unroll
        for (int d4 = 0; d4 < 4; ++d4) {
            const float4 kf = *(const float4*)(kp + d4 * 4);
            acc += qr[d4 * 4 + 0] * kf.x + qr[d4 * 4 + 1] * kf.y
                 + qr[d4 * 4 + 2] * kf.z + qr[d4 * 4 + 3] * kf.w;
        }
        lg[q] = acc;
        m = fmaxf(m, acc);
    }

    float s = 0.f;
    #pragma unroll
    for (int q = 0; q < KS; ++q) { lg[q] = __expf(lg[q] - m); s += lg[q]; }

    // ---- partial PV (pure fma) ----
    float o[HD];
    #pragma unroll
    for (int d = 0; d < HD; ++d) o[d] = 0.f;
    #pragma unroll
    for (int q = 0; q < KS; ++q) {
        const float* vp = &kvV[(posr + q) * KVP32 + hh * HD];
        const float wgt = lg[q];
        #pragma unroll
        for (int d4 = 0; d4 < 4; ++d4) {
            const float4 vf = *(const float4*)(vp + d4 * 4);
            o[d4 * 4 + 0] += wgt * vf.x;
            o[d4 * 4 + 1] += wgt * vf.y;
            o[d4 * 4 + 2] += wgt * vf.z;
            o[d4 * 4 + 3] += wgt * vf.w;
        }
    }

    // ---- online-softmax butterfly merge across r (lane bits 3..5) ----
    #pragma unroll
    for (int mask = 8; mask <= 32; mask <<= 1) {
        const float m2 = __shfl_xor(m, mask);
        const float s2 = __shfl_xor(s, mask);
        const float mn = fmaxf(m, m2);
        const float ea = __expf(m - mn);
        const float eb = __expf(m2 - mn);
        s = s * ea + s2 * eb;
        #pragma unroll
        for (int d = 0; d < HD; ++d) {
            const float o2 = __shfl_xor(o[d], mask);
            o[d] = o[d] * ea + o2 * eb;
        }
        m = mn;
    }
    const float inv = 1.f / s;

    a_t[(size_t)(h * HD + 2 * r)     * NPIX + pix] = o[2 * r]     * inv;
    a_t[(size_t)(h * HD + 2 * r + 1) * NPIX + pix] = o[2 * r + 1] * inv;
}

// ---------------------------------------------------------------------------
// K3: 1x1 projection, ILP layout (R12 proven, byte-identical).
// ---------------------------------------------------------------------------
__global__ __launch_bounds__(256) void proj_kernel(
    const float* __restrict__ a_t,      // [CH][NPIX]
    const float* __restrict__ pw,       // [128][128] ([o][c])
    const float* __restrict__ pb,       // [128]
    float* __restrict__ out)            // [128][NPIX]
{
    const int idx = blockIdx.x * 256 + threadIdx.x;
    const int op  = __builtin_amdgcn_readfirstlane(idx / 2304);  // 0..63
    const int pq  = idx - op * 2304;
    const int px0 = pq * 4;
    const int o0  = op * 2;

    float acc0[4], acc1[4];
    #pragma unroll
    for (int e = 0; e < 4; ++e) { acc0[e] = pb[o0]; acc1[e] = pb[o0 + 1]; }

    for (int c = 0; c < CH; ++c) {
        const float4 a  = *(const float4*)(a_t + (size_t)c * NPIX + px0);
        const float  w0 = pw[(o0)     * CH + c];
        const float  w1 = pw[(o0 + 1) * CH + c];
        acc0[0] += a.x * w0; acc0[1] += a.y * w0; acc0[2] += a.z * w0; acc0[3] += a.w * w0;
        acc1[0] += a.x * w1; acc1[1] += a.y * w1; acc1[2] += a.z * w1; acc1[3] += a.w * w1;
    }

    *(float4*)(out + (size_t)(o0)     * NPIX + px0) = make_float4(acc0[0], acc0[1], acc0[2], acc0[3]);
    *(float4*)(out + (size_t)(o0 + 1) * NPIX + px0) = make_float4(acc1[0], acc1[1], acc1[2], acc1[3]);
}

// ---------------------------------------------------------------------------
extern "C" void kernel_launch(void* const* d_in, const int* in_sizes, int n_in,
                              void* d_out, int out_size, void* d_ws, size_t ws_size,
                              hipStream_t stream)
{
    const float* x      = (const float*)d_in[0];
    const float* qkv_w  = (const float*)d_in[1];
    const float* qkv_b  = (const float*)d_in[2];
    const float* proj_w = (const float*)d_in[3];
    const float* proj_b = (const float*)d_in[4];
    float* out = (float*)d_out;

    unsigned short* qkv_pm = (unsigned short*)d_ws;            // [3][NPIX][CH] bf16 (7.08 MB)
    float*          a_t    = (float*)(qkv_pm + 3 * NPIX * CH); // [CH][NPIX] fp32 (4.72 MB)

    conv_pm_kernel<<<384, 256, 0, stream>>>(x, qkv_w, qkv_b, qkv_pm);
    attn_kernel   <<<dim3(576, 4), 256, 0, stream>>>(qkv_pm, a_t);
    proj_kernel   <<<576, 256, 0, stream>>>(a_t, proj_w, proj_b, out);
}

// Round 17
// 103.524 us; speedup vs baseline: 4.3374x; 1.0228x over previous
//
#include <hip/hip_runtime.h>
#include <hip/hip_bf16.h>

// Problem constants (B=1). All inputs/outputs are float32.
#define HH   96
#define WW   96
#define NPIX 9216          // 96*96
#define CH   128
#define NH   8
#define HD   16
#define KS   8

#define NEPIX   2304       // 48*48 even-even grid (k/v only ever read there)
#define NPOS    120        // 8 window rows x 15 window cols per 16-px segment
#define KVPITCH 40         // attn LDS pitch in channels (80B/pos)
#define QTPITCH 136        // conv q-tile pitch (ch)
#define KVTPITCH 264       // conv kv-tile pitch (ch, k+v = 256 + pad)

__device__ __forceinline__ unsigned short f2bf(float f) {
    __hip_bfloat16 b = __float2bfloat16(f);
    union { __hip_bfloat16 b; unsigned short u; } cv; cv.b = b; return cv.u;
}
// unpack uint4 = 8 bf16 -> 8 fp32
__device__ __forceinline__ void u4_to_f8(uint4 u, float* f) {
    f[0] = __uint_as_float(u.x << 16); f[1] = __uint_as_float(u.x & 0xffff0000u);
    f[2] = __uint_as_float(u.y << 16); f[3] = __uint_as_float(u.y & 0xffff0000u);
    f[4] = __uint_as_float(u.z << 16); f[5] = __uint_as_float(u.z & 0xffff0000u);
    f[6] = __uint_as_float(u.w << 16); f[7] = __uint_as_float(u.w & 0xffff0000u);
}

// ---------------------------------------------------------------------------
// K1: depthwise 3x3 conv. q computed at ALL pixels -> q_pm [NPIX][CH];
// k/v computed ONLY at even-even pixels (the only ones attention reads,
// since stride=2 centers + dil=2 windows land on even coords) -> compact
// kv_pm [2][NEPIX][CH]. 2x less conv FMA, half the staging bytes of R12.
// Grid 384 (row x quarter); block 256 = (g = tid>>1, sh = tid&1 -> 12 px).
// Conv math per-output identical to the R12-proven kernel.
// ---------------------------------------------------------------------------
__global__ __launch_bounds__(256) void conv_kernel(
    const float* __restrict__ x,        // [128][96][96]
    const float* __restrict__ w,        // [384][1][3][3]
    const float* __restrict__ bias,     // [384]
    unsigned short* __restrict__ q_pm,  // [NPIX][CH] bf16
    unsigned short* __restrict__ kv_pm) // [2][NEPIX][CH] bf16
{
    __shared__ unsigned short qt [24 * QTPITCH];    // 6,528 B
    __shared__ unsigned short kvt[12 * KVTPITCH];   // 6,336 B

    const int row = blockIdx.x >> 2;    // 0..95
    const int qtr = blockIdx.x & 3;     // 0..3
    const int j0q = qtr * 24;
    const int tid = threadIdx.x;
    const int g   = tid >> 1;           // 0..127 input channel / group
    const int sh  = tid & 1;            // 0/1 -> 12 px each
    const int j0  = j0q + sh * 12;      // even (24-multiples + 0/12)
    const bool kvrow = (row & 1) == 0;  // block-uniform

    const float* xg = x + g * NPIX;

    float xr[3][14];
    #pragma unroll
    for (int dr = 0; dr < 3; ++dr) {
        const int r = row + dr - 1;
        if (r >= 0 && r < HH) {
            #pragma unroll
            for (int m = 0; m < 14; ++m) {
                const int j = j0 + m - 1;
                xr[dr][m] = (j >= 0 && j < WW) ? xg[r * WW + j] : 0.f;
            }
        } else {
            #pragma unroll
            for (int m = 0; m < 14; ++m) xr[dr][m] = 0.f;
        }
    }

    #pragma unroll
    for (int dt = 0; dt < 3; ++dt) {
        const int o = 3 * g + dt;       // conv out-channel (group g)
        const int t = o >> 7;           // 0=q, 1=k, 2=v
        const int c = o & 127;
        float w9[9];
        #pragma unroll
        for (int k = 0; k < 9; ++k) w9[k] = w[o * 9 + k];
        const float b = bias[o];

        if (t == 0) {
            #pragma unroll
            for (int px = 0; px < 12; ++px) {
                float acc = b;
                #pragma unroll
                for (int kh = 0; kh < 3; ++kh)
                    #pragma unroll
                    for (int kw = 0; kw < 3; ++kw)
                        acc += xr[kh][px + kw] * w9[kh * 3 + kw];
                qt[(sh * 12 + px) * QTPITCH + c] = f2bf(acc);
            }
        } else if (kvrow) {
            #pragma unroll
            for (int pe = 0; pe < 6; ++pe) {        // even px only
                const int px = pe * 2;
                float acc = b;
                #pragma unroll
                for (int kh = 0; kh < 3; ++kh)
                    #pragma unroll
                    for (int kw = 0; kw < 3; ++kw)
                        acc += xr[kh][px + kw] * w9[kh * 3 + kw];
                kvt[(sh * 6 + pe) * KVTPITCH + (t - 1) * CH + c] = f2bf(acc);
            }
        }
    }

    __syncthreads();

    // write q: 24 px x 16 uint4 = 384 tasks; kv (even rows): +384 tasks
    const int ntask = kvrow ? 768 : 384;
    #pragma unroll
    for (int it = 0; it < 3; ++it) {
        const int idx = it * 256 + tid;
        if (idx < 384) {
            const int px  = idx >> 4;           // 0..23
            const int c8  = (idx & 15) * 8;
            const uint4 v = *(const uint4*)&qt[px * QTPITCH + c8];
            *(uint4*)(q_pm + ((size_t)(row * WW) + j0q + px) * CH + c8) = v;
        } else if (idx < ntask) {
            const int k2  = idx - 384;
            const int epx = k2 >> 5;            // 0..11
            const int c32 = (k2 & 31) * 8;      // 0..255 ch (k then v)
            const int t1  = c32 >> 7;           // 0=k, 1=v
            const int c   = c32 & 127;
            const uint4 v = *(const uint4*)&kvt[epx * KVTPITCH + c32];
            *(uint4*)(kv_pm + ((size_t)t1 * NEPIX + (row >> 1) * 48
                               + (j0q >> 1) + epx) * CH + c) = v;
        }
    }
}

// ---------------------------------------------------------------------------
// K2: neighborhood attention, head-pair blocks (R12-proven body); staging
// now reads the compact even-even kv_pm (window cols CONTIGUOUS there).
// Grid (576 segs, 4 head-pairs); block = 256 thr = 16 px x 2 heads x 8 r.
// LDS 19.2 KB -> 8 blocks/CU = 32 waves/CU. Merge across r via __shfl_xor.
// ---------------------------------------------------------------------------
__global__ __launch_bounds__(256) void attn_kernel(
    const unsigned short* __restrict__ q_pm,    // [NPIX][CH] bf16
    const unsigned short* __restrict__ kv_pm,   // [2][NEPIX][CH] bf16
    float* __restrict__ a_t)                    // [CH][NPIX] fp32
{
    __shared__ unsigned short kv[2][NPOS * KVPITCH];   // 19,200 B

    const int tid = threadIdx.x;
    const int seg = blockIdx.x;                 // 0..575
    const int hp  = blockIdx.y;                 // head pair 0..3
    const int i   = seg / 6;                    // image row
    const int j0  = (seg - i * 6) * 16;
    const int rs     = 2 * min(max(i / 2 - 3, 0), 40);
    const int cs_min = 2 * min(max(j0 / 2 - 3, 0), 40);
    const int er0 = rs >> 1;                    // compact window row base
    const int ec0 = cs_min >> 1;                // compact window col base

    // ---- stage K,V head-pair slice: 960 uint4 tasks ----
    #pragma unroll
    for (int it = 0; it < 4; ++it) {
        const int idx = it * 256 + tid;
        if (idx < 960) {
            const int kvsel = idx / 480;
            const int rem   = idx - kvsel * 480;
            const int pos   = rem >> 2;
            const int sub   = rem & 3;
            const int p     = pos / 15;
            const int cc    = pos - p * 15;
            const int ec    = min(ec0 + cc, 47);        // clamp: cc>=11 at the
            const int ep    = (er0 + p) * 48 + ec;      // right edge is unused
            *(uint4*)&kv[kvsel][pos * KVPITCH + sub * 8] =
                *(const uint4*)(kv_pm + ((size_t)kvsel * NEPIX + ep) * CH
                                + hp * 32 + sub * 8);
        }
    }

    // ---- per-thread coordinates: lane = r*8 + hh*4 + px_lo ----
    const int lane  = tid & 63;
    const int wave  = tid >> 6;                 // 0..3
    const int r     = lane >> 3;                // window-row split
    const int hh    = (lane >> 2) & 1;          // head within pair
    const int px    = wave * 4 + (lane & 3);    // 0..15
    const int h     = hp * 2 + hh;
    const int pix   = seg * 16 + px;
    const int j     = j0 + px;
    const int ci0   = (2 * min(max(j / 2 - 3, 0), 40) - cs_min) >> 1;  // 0..7

    float qr[HD];
    {
        const unsigned short* qp = q_pm + (size_t)pix * CH + h * HD;
        u4_to_f8(*(const uint4*)qp, qr);
        u4_to_f8(*(const uint4*)(qp + 8), qr + 8);
        #pragma unroll
        for (int d = 0; d < HD; ++d) qr[d] *= 0.25f;   // HD^-0.5
    }

    __syncthreads();

    const int posr = r * 15 + ci0;
    float lg[KS];
    float m = -1e30f;
    #pragma unroll
    for (int q = 0; q < KS; ++q) {
        const unsigned short* kp = &kv[0][(posr + q) * KVPITCH + hh * HD];
        float kf[HD];
        u4_to_f8(*(const uint4*)kp, kf);
        u4_to_f8(*(const uint4*)(kp + 8), kf + 8);
        float acc = 0.f;
        #pragma unroll
        for (int d = 0; d < HD; ++d) acc += qr[d] * kf[d];
        lg[q] = acc;
        m = fmaxf(m, acc);
    }

    float s = 0.f;
    #pragma unroll
    for (int q = 0; q < KS; ++q) { lg[q] = __expf(lg[q] - m); s += lg[q]; }

    float o[HD];
    #pragma unroll
    for (int d = 0; d < HD; ++d) o[d] = 0.f;
    #pragma unroll
    for (int q = 0; q < KS; ++q) {
        const unsigned short* vp = &kv[1][(posr + q) * KVPITCH + hh * HD];
        float vf[HD];
        u4_to_f8(*(const uint4*)vp, vf);
        u4_to_f8(*(const uint4*)(vp + 8), vf + 8);
        const float wgt = lg[q];
        #pragma unroll
        for (int d = 0; d < HD; ++d) o[d] += wgt * vf[d];
    }

    #pragma unroll
    for (int mask = 8; mask <= 32; mask <<= 1) {
        const float m2 = __shfl_xor(m, mask);
        const float s2 = __shfl_xor(s, mask);
        const float mn = fmaxf(m, m2);
        const float ea = __expf(m - mn);
        const float eb = __expf(m2 - mn);
        s = s * ea + s2 * eb;
        #pragma unroll
        for (int d = 0; d < HD; ++d) {
            const float o2 = __shfl_xor(o[d], mask);
            o[d] = o[d] * ea + o2 * eb;
        }
        m = mn;
    }
    const float inv = 1.f / s;

    a_t[(size_t)(h * HD + 2 * r)     * NPIX + pix] = o[2 * r]     * inv;
    a_t[(size_t)(h * HD + 2 * r + 1) * NPIX + pix] = o[2 * r + 1] * inv;
}

// ---------------------------------------------------------------------------
// K3: 1x1 projection, ILP layout (R12 proven, byte-identical).
// ---------------------------------------------------------------------------
__global__ __launch_bounds__(256) void proj_kernel(
    const float* __restrict__ a_t,      // [CH][NPIX]
    const float* __restrict__ pw,       // [128][128] ([o][c])
    const float* __restrict__ pb,       // [128]
    float* __restrict__ out)            // [128][NPIX]
{
    const int idx = blockIdx.x * 256 + threadIdx.x;
    const int op  = __builtin_amdgcn_readfirstlane(idx / 2304);  // 0..63
    const int pq  = idx - op * 2304;
    const int px0 = pq * 4;
    const int o0  = op * 2;

    float acc0[4], acc1[4];
    #pragma unroll
    for (int e = 0; e < 4; ++e) { acc0[e] = pb[o0]; acc1[e] = pb[o0 + 1]; }

    for (int c = 0; c < CH; ++c) {
        const float4 a  = *(const float4*)(a_t + (size_t)c * NPIX + px0);
        const float  w0 = pw[(o0)     * CH + c];
        const float  w1 = pw[(o0 + 1) * CH + c];
        acc0[0] += a.x * w0; acc0[1] += a.y * w0; acc0[2] += a.z * w0; acc0[3] += a.w * w0;
        acc1[0] += a.x * w1; acc1[1] += a.y * w1; acc1[2] += a.z * w1; acc1[3] += a.w * w1;
    }

    *(float4*)(out + (size_t)(o0)     * NPIX + px0) = make_float4(acc0[0], acc0[1], acc0[2], acc0[3]);
    *(float4*)(out + (size_t)(o0 + 1) * NPIX + px0) = make_float4(acc1[0], acc1[1], acc1[2], acc1[3]);
}

// ---------------------------------------------------------------------------
extern "C" void kernel_launch(void* const* d_in, const int* in_sizes, int n_in,
                              void* d_out, int out_size, void* d_ws, size_t ws_size,
                              hipStream_t stream)
{
    const float* x      = (const float*)d_in[0];
    const float* qkv_w  = (const float*)d_in[1];
    const float* qkv_b  = (const float*)d_in[2];
    const float* proj_w = (const float*)d_in[3];
    const float* proj_b = (const float*)d_in[4];
    float* out = (float*)d_out;

    // ws: [q_pm 2.36 MB][kv_pm 1.18 MB][a_t 4.72 MB]
    unsigned short* q_pm  = (unsigned short*)d_ws;             // [NPIX][CH]
    unsigned short* kv_pm = q_pm + (size_t)NPIX * CH;          // [2][NEPIX][CH]
    float*          a_t   = (float*)(kv_pm + (size_t)2 * NEPIX * CH);

    conv_kernel<<<384, 256, 0, stream>>>(x, qkv_w, qkv_b, q_pm, kv_pm);
    attn_kernel<<<dim3(576, 4), 256, 0, stream>>>(q_pm, kv_pm, a_t);
    proj_kernel<<<576, 256, 0, stream>>>(a_t, proj_w, proj_b, out);
}